// Round 3
// baseline (3314.024 us; speedup 1.0000x reference)
//
#include <hip/hip_runtime.h>
#include <math.h>

// Problem constants (match reference)
#define NN      50000
#define IND     256
#define HH      8
#define DD      32
#define DMODEL  256      // H*D
#define AA      8
#define EE      800000
#define HALF    128      // DMODEL/2

// Workspace layout (float element offsets)
#define P_OFF   0                         // softmax(S): 8*128
#define Q_OFF   1024
#define K_OFF   (Q_OFF + NN*DMODEL)       // 12,800,000 each
#define V_OFF   (K_OFF + NN*DMODEL)
#define W_OFF   (V_OFF + NN*DMODEL)       // per-edge exp weights: E*H
#define DEN_OFF (W_OFF + EE*HH)           // per-(node,head) denom: N*H

// ---------------------------------------------------------------------------
// P = softmax(S, axis=1)   S:[8,128] -> one block, wave per row
// ---------------------------------------------------------------------------
__global__ __launch_bounds__(512) void softmax_S(const float* __restrict__ S,
                                                 float* __restrict__ P) {
    const int wave = threadIdx.x >> 6;   // row a = 0..7
    const int lane = threadIdx.x & 63;
    const float* row = S + wave * HALF;
    float s0 = row[lane], s1 = row[lane + 64];
    float m = fmaxf(s0, s1);
    #pragma unroll
    for (int off = 32; off; off >>= 1) m = fmaxf(m, __shfl_xor(m, off));
    float e0 = expf(s0 - m), e1 = expf(s1 - m);
    float sum = e0 + e1;
    #pragma unroll
    for (int off = 32; off; off >>= 1) sum += __shfl_xor(sum, off);
    float inv = 1.0f / sum;
    P[wave * HALF + lane]      = e0 * inv;
    P[wave * HALF + lane + 64] = e1 * inv;
}

// ---------------------------------------------------------------------------
// Fused QKV projection: O[n, 0:768] = x[n,:] @ [Wq|Wk|Wv] + [bq|bk|bv]
// Tiled fp32 SGEMM: 64x64 tile / block(256), 4x4 microtile / thread.
// blockIdx.y selects the 64-col tile; tiles never span matrices (256/64=4).
// ---------------------------------------------------------------------------
__global__ __launch_bounds__(256) void qkv_gemm(
    const float* __restrict__ x,
    const float* __restrict__ Wq, const float* __restrict__ bq,
    const float* __restrict__ Wk, const float* __restrict__ bk,
    const float* __restrict__ Wv, const float* __restrict__ bv,
    float* __restrict__ Q, float* __restrict__ K, float* __restrict__ V) {
    __shared__ float As[16][64];   // A tile transposed: As[k][row]
    __shared__ float Bs[16][64];

    const int t = threadIdx.x;
    const int row0 = blockIdx.x * 64;
    const int colTile = blockIdx.y;            // 0..11
    const int which = colTile >> 2;            // 0=Q 1=K 2=V
    const int col0 = (colTile & 3) * 64;       // col base within matrix
    const float* __restrict__ W    = (which == 0) ? Wq : (which == 1) ? Wk : Wv;
    const float* __restrict__ bias = (which == 0) ? bq : (which == 1) ? bk : bv;
    float* __restrict__ O          = (which == 0) ? Q  : (which == 1) ? K  : V;

    const int tr = (t >> 4) << 2;   // microtile row base 0..60
    const int tc = (t & 15) << 2;   // microtile col base 0..60
    const int ar = t >> 2;          // A-load row 0..63
    const int ak = (t & 3) << 2;    // A-load k base {0,4,8,12}
    const int brow = t >> 4;        // B-load k 0..15
    const int bcol = (t & 15) << 2; // B-load col base
    const int grow = row0 + ar;
    const bool a_ok = (grow < NN);

    float acc[4][4] = {{0.f, 0.f, 0.f, 0.f}, {0.f, 0.f, 0.f, 0.f},
                       {0.f, 0.f, 0.f, 0.f}, {0.f, 0.f, 0.f, 0.f}};

    for (int k0 = 0; k0 < IND; k0 += 16) {
        float4 a4 = a_ok ? *(const float4*)(x + grow * IND + k0 + ak)
                         : make_float4(0.f, 0.f, 0.f, 0.f);
        float4 b4 = *(const float4*)(W + (k0 + brow) * DMODEL + col0 + bcol);
        __syncthreads();
        As[ak + 0][ar] = a4.x; As[ak + 1][ar] = a4.y;
        As[ak + 2][ar] = a4.z; As[ak + 3][ar] = a4.w;
        *(float4*)&Bs[brow][bcol] = b4;
        __syncthreads();
        #pragma unroll
        for (int kk = 0; kk < 16; ++kk) {
            const float4 a = *(const float4*)&As[kk][tr];
            const float4 b = *(const float4*)&Bs[kk][tc];
            acc[0][0] = fmaf(a.x, b.x, acc[0][0]); acc[0][1] = fmaf(a.x, b.y, acc[0][1]);
            acc[0][2] = fmaf(a.x, b.z, acc[0][2]); acc[0][3] = fmaf(a.x, b.w, acc[0][3]);
            acc[1][0] = fmaf(a.y, b.x, acc[1][0]); acc[1][1] = fmaf(a.y, b.y, acc[1][1]);
            acc[1][2] = fmaf(a.y, b.z, acc[1][2]); acc[1][3] = fmaf(a.y, b.w, acc[1][3]);
            acc[2][0] = fmaf(a.z, b.x, acc[2][0]); acc[2][1] = fmaf(a.z, b.y, acc[2][1]);
            acc[2][2] = fmaf(a.z, b.z, acc[2][2]); acc[2][3] = fmaf(a.z, b.w, acc[2][3]);
            acc[3][0] = fmaf(a.w, b.x, acc[3][0]); acc[3][1] = fmaf(a.w, b.y, acc[3][1]);
            acc[3][2] = fmaf(a.w, b.z, acc[3][2]); acc[3][3] = fmaf(a.w, b.w, acc[3][3]);
        }
    }
    const float4 bb = *(const float4*)(bias + col0 + tc);
    #pragma unroll
    for (int i = 0; i < 4; ++i) {
        int n = row0 + tr + i;
        if (n < NN) {
            float4 o;
            o.x = acc[i][0] + bb.x; o.y = acc[i][1] + bb.y;
            o.z = acc[i][2] + bb.z; o.w = acc[i][3] + bb.w;
            *(float4*)(O + n * DMODEL + col0 + tc) = o;
        }
    }
}

// ---------------------------------------------------------------------------
// Learned-RoPE rotation of Q and K, in place. One block per node.
// thetas[n,j] = sum_a ang[n,a]*P[a,j]; rep-interleaved by 2 over DMODEL.
// rotate_half within head: out[d<16] pairs -in[2d+1]; out[d>=16] pairs +in[2(d-16)]
// ---------------------------------------------------------------------------
__global__ __launch_bounds__(256) void rotate_qk(float* __restrict__ Q,
                                                 float* __restrict__ K,
                                                 const float* __restrict__ ang,
                                                 const float* __restrict__ P) {
    __shared__ float cbuf[HALF], sbuf[HALF];
    const int n = blockIdx.x;
    const int t = threadIdx.x;
    if (t < HALF) {
        float th = 0.f;
        #pragma unroll
        for (int a = 0; a < AA; ++a) th = fmaf(ang[n * AA + a], P[a * HALF + t], th);
        cbuf[t] = cosf(th);
        sbuf[t] = sinf(th);
    }
    __syncthreads();
    const int hd = t & 31;               // dim within head
    const int rowb = n * DMODEL;
    const int headb = t & ~31;           // head base within row
    const int pl = (hd < 16) ? (headb + 2 * hd + 1) : (headb + 2 * (hd - 16));
    const float sgn = (hd < 16) ? -1.f : 1.f;
    const float c = cbuf[t >> 1], s = sbuf[t >> 1];
    const float qv = Q[rowb + t], qp = Q[rowb + pl];
    const float kv = K[rowb + t], kp = K[rowb + pl];
    __syncthreads();   // all reads complete before in-place writes
    Q[rowb + t] = fmaf(qv, c, sgn * qp * s);
    K[rowb + t] = fmaf(kv, c, sgn * kp * s);
}

// ---------------------------------------------------------------------------
// Edge pass 1 (wave-per-edge, coalesced): lane r reads float4 at element 4r
// of K[src] and Q[dst] rows (64 lanes x 16B = the full 1KB row, contiguous).
// Head h = r>>3 spans lanes 8h..8h+7 (elements 32h..32h+31). 3-step
// shfl_xor reduce inside each 8-lane group; group leader does exp + atomics.
// Scores clamped to +-5 -> exp without segment-max subtraction is exact
// to ~1e-12 relative vs the reference's max-subtracted form.
// ---------------------------------------------------------------------------
__global__ __launch_bounds__(256) void edge_score(const float* __restrict__ Q,
                                                  const float* __restrict__ K,
                                                  const int* __restrict__ ei,
                                                  float* __restrict__ w,
                                                  float* __restrict__ den) {
    const unsigned gid = blockIdx.x * 256u + threadIdx.x;   // E*64 threads
    const int e = gid >> 6;
    const int r = gid & 63;
    const int src = ei[e], dst = ei[EE + e];
    const float4 kv = *(const float4*)(K + src * DMODEL + r * 4);
    const float4 qv = *(const float4*)(Q + dst * DMODEL + r * 4);
    float p = kv.x * qv.x;
    p = fmaf(kv.y, qv.y, p);
    p = fmaf(kv.z, qv.z, p);
    p = fmaf(kv.w, qv.w, p);
    // reduce within 8-lane head group
    p += __shfl_xor(p, 1);
    p += __shfl_xor(p, 2);
    p += __shfl_xor(p, 4);
    if ((r & 7) == 0) {
        const int h = r >> 3;
        float sc = p * 0.17677669529663687f;   // 1/sqrt(32)
        sc = fminf(fmaxf(sc, -5.f), 5.f);
        const float wv = expf(sc);
        w[(e << 3) + h] = wv;
        unsafeAtomicAdd(&den[dst * HH + h], wv);
    }
}

// ---------------------------------------------------------------------------
// den -> 1/(den+eps), in place.  N*H = 400k elements.
// ---------------------------------------------------------------------------
__global__ __launch_bounds__(256) void invert_den(float* __restrict__ den) {
    const unsigned i = blockIdx.x * 256u + threadIdx.x;
    if (i < NN * HH) den[i] = 1.0f / (den[i] + 1e-16f);
}

// ---------------------------------------------------------------------------
// Edge pass 2: out[dst,h,:] += V[src,h,:] * w[e,h]*inv_den[dst,h]
// One wave per edge (lane r handles float4 at element r*4 of the 256-row).
// ---------------------------------------------------------------------------
__global__ __launch_bounds__(256) void aggregate(const float* __restrict__ V,
                                                 const int* __restrict__ ei,
                                                 const float* __restrict__ w,
                                                 const float* __restrict__ inv_den,
                                                 float* __restrict__ out) {
    const unsigned gid = blockIdx.x * 256u + threadIdx.x;   // exactly E*64 threads
    const int e = gid >> 6;
    const int r = gid & 63;
    const int h = r >> 3;
    const int src = ei[e], dst = ei[EE + e];
    const float a = w[(e << 3) + h] * inv_den[dst * HH + h];
    const float4 v = *(const float4*)(V + src * DMODEL + r * 4);
    float* op = out + dst * DMODEL + r * 4;
    unsafeAtomicAdd(op + 0, v.x * a);
    unsafeAtomicAdd(op + 1, v.y * a);
    unsafeAtomicAdd(op + 2, v.z * a);
    unsafeAtomicAdd(op + 3, v.w * a);
}

// ---------------------------------------------------------------------------
extern "C" void kernel_launch(void* const* d_in, const int* in_sizes, int n_in,
                              void* d_out, int out_size, void* d_ws, size_t ws_size,
                              hipStream_t stream) {
    (void)in_sizes; (void)n_in; (void)out_size; (void)ws_size;
    const float* x    = (const float*)d_in[0];
    const float* ang  = (const float*)d_in[1];
    const int*   ei   = (const int*)d_in[2];
    const float* Wq   = (const float*)d_in[3];
    const float* bq   = (const float*)d_in[4];
    const float* Wk   = (const float*)d_in[5];
    const float* bk   = (const float*)d_in[6];
    const float* Wv   = (const float*)d_in[7];
    const float* bv   = (const float*)d_in[8];
    const float* S    = (const float*)d_in[9];
    float* out = (float*)d_out;
    float* ws  = (float*)d_ws;

    float* P   = ws + P_OFF;
    float* Q   = ws + Q_OFF;
    float* K   = ws + K_OFF;
    float* V   = ws + V_OFF;
    float* w   = ws + W_OFF;
    float* den = ws + DEN_OFF;

    // zero the accumulators (d_out / d_ws are poisoned before every call)
    hipMemsetAsync(out, 0, (size_t)NN * DMODEL * sizeof(float), stream);
    hipMemsetAsync(den, 0, (size_t)NN * HH * sizeof(float), stream);

    softmax_S<<<1, 512, 0, stream>>>(S, P);

    dim3 ggrid((NN + 63) / 64, 12);
    qkv_gemm<<<ggrid, 256, 0, stream>>>(x, Wq, bq, Wk, bk, Wv, bv, Q, K, V);

    rotate_qk<<<NN, 256, 0, stream>>>(Q, K, ang, P);

    edge_score<<<(EE * 64) / 256, 256, 0, stream>>>(Q, K, ei, w, den);

    invert_den<<<(NN * HH + 255) / 256, 256, 0, stream>>>(den);

    aggregate<<<(EE * 64) / 256, 256, 0, stream>>>(V, ei, w, den, out);
}

// Round 4
// 782.983 us; speedup vs baseline: 4.2326x; 4.2326x over previous
//
#include <hip/hip_runtime.h>
#include <math.h>

// Problem constants (match reference)
#define NN      50000
#define IND     256
#define HH      8
#define DD      32
#define DMODEL  256      // H*D
#define AA      8
#define EE      800000
#define HALF    128      // DMODEL/2

// Workspace layout (float-element offsets)
#define P_OFF    0                          // softmax(S): 8*128
#define Q_OFF    1024
#define K_OFF    (Q_OFF + NN*DMODEL)
#define V_OFF    (K_OFF + NN*DMODEL)
#define INT_OFF  (V_OFF + NN*DMODEL)        // int region starts here
// int-element offsets within the int region:
#define CNT_I    0                          // cnt[NN]
#define OFF_I    (CNT_I + NN)               // off[NN+1]
#define CUR_I    (OFF_I + NN + 1)           // cursor[NN]
#define PSRC_I   (CUR_I + NN)               // psrc[EE]

// ---------------------------------------------------------------------------
// P = softmax(S, axis=1)   S:[8,128] -> one block, wave per row
// ---------------------------------------------------------------------------
__global__ __launch_bounds__(512) void softmax_S(const float* __restrict__ S,
                                                 float* __restrict__ P) {
    const int wave = threadIdx.x >> 6;   // row a = 0..7
    const int lane = threadIdx.x & 63;
    const float* row = S + wave * HALF;
    float s0 = row[lane], s1 = row[lane + 64];
    float m = fmaxf(s0, s1);
    #pragma unroll
    for (int off = 32; off; off >>= 1) m = fmaxf(m, __shfl_xor(m, off));
    float e0 = expf(s0 - m), e1 = expf(s1 - m);
    float sum = e0 + e1;
    #pragma unroll
    for (int off = 32; off; off >>= 1) sum += __shfl_xor(sum, off);
    float inv = 1.0f / sum;
    P[wave * HALF + lane]      = e0 * inv;
    P[wave * HALF + lane + 64] = e1 * inv;
}

// ---------------------------------------------------------------------------
// Fused QKV projection: O[n, 0:768] = x[n,:] @ [Wq|Wk|Wv] + [bq|bk|bv]
// Tiled fp32 SGEMM: 64x64 tile / block(256), 4x4 microtile / thread.
// ---------------------------------------------------------------------------
__global__ __launch_bounds__(256) void qkv_gemm(
    const float* __restrict__ x,
    const float* __restrict__ Wq, const float* __restrict__ bq,
    const float* __restrict__ Wk, const float* __restrict__ bk,
    const float* __restrict__ Wv, const float* __restrict__ bv,
    float* __restrict__ Q, float* __restrict__ K, float* __restrict__ V) {
    __shared__ float As[16][64];   // A tile transposed: As[k][row]
    __shared__ float Bs[16][64];

    const int t = threadIdx.x;
    const int row0 = blockIdx.x * 64;
    const int colTile = blockIdx.y;            // 0..11
    const int which = colTile >> 2;            // 0=Q 1=K 2=V
    const int col0 = (colTile & 3) * 64;       // col base within matrix
    const float* __restrict__ W    = (which == 0) ? Wq : (which == 1) ? Wk : Wv;
    const float* __restrict__ bias = (which == 0) ? bq : (which == 1) ? bk : bv;
    float* __restrict__ O          = (which == 0) ? Q  : (which == 1) ? K  : V;

    const int tr = (t >> 4) << 2;   // microtile row base 0..60
    const int tc = (t & 15) << 2;   // microtile col base 0..60
    const int ar = t >> 2;          // A-load row 0..63
    const int ak = (t & 3) << 2;    // A-load k base {0,4,8,12}
    const int brow = t >> 4;        // B-load k 0..15
    const int bcol = (t & 15) << 2; // B-load col base
    const int grow = row0 + ar;
    const bool a_ok = (grow < NN);

    float acc[4][4] = {{0.f, 0.f, 0.f, 0.f}, {0.f, 0.f, 0.f, 0.f},
                       {0.f, 0.f, 0.f, 0.f}, {0.f, 0.f, 0.f, 0.f}};

    for (int k0 = 0; k0 < IND; k0 += 16) {
        float4 a4 = a_ok ? *(const float4*)(x + grow * IND + k0 + ak)
                         : make_float4(0.f, 0.f, 0.f, 0.f);
        float4 b4 = *(const float4*)(W + (k0 + brow) * DMODEL + col0 + bcol);
        __syncthreads();
        As[ak + 0][ar] = a4.x; As[ak + 1][ar] = a4.y;
        As[ak + 2][ar] = a4.z; As[ak + 3][ar] = a4.w;
        *(float4*)&Bs[brow][bcol] = b4;
        __syncthreads();
        #pragma unroll
        for (int kk = 0; kk < 16; ++kk) {
            const float4 a = *(const float4*)&As[kk][tr];
            const float4 b = *(const float4*)&Bs[kk][tc];
            acc[0][0] = fmaf(a.x, b.x, acc[0][0]); acc[0][1] = fmaf(a.x, b.y, acc[0][1]);
            acc[0][2] = fmaf(a.x, b.z, acc[0][2]); acc[0][3] = fmaf(a.x, b.w, acc[0][3]);
            acc[1][0] = fmaf(a.y, b.x, acc[1][0]); acc[1][1] = fmaf(a.y, b.y, acc[1][1]);
            acc[1][2] = fmaf(a.y, b.z, acc[1][2]); acc[1][3] = fmaf(a.y, b.w, acc[1][3]);
            acc[2][0] = fmaf(a.z, b.x, acc[2][0]); acc[2][1] = fmaf(a.z, b.y, acc[2][1]);
            acc[2][2] = fmaf(a.z, b.z, acc[2][2]); acc[2][3] = fmaf(a.z, b.w, acc[2][3]);
            acc[3][0] = fmaf(a.w, b.x, acc[3][0]); acc[3][1] = fmaf(a.w, b.y, acc[3][1]);
            acc[3][2] = fmaf(a.w, b.z, acc[3][2]); acc[3][3] = fmaf(a.w, b.w, acc[3][3]);
        }
    }
    const float4 bb = *(const float4*)(bias + col0 + tc);
    #pragma unroll
    for (int i = 0; i < 4; ++i) {
        int n = row0 + tr + i;
        if (n < NN) {
            float4 o;
            o.x = acc[i][0] + bb.x; o.y = acc[i][1] + bb.y;
            o.z = acc[i][2] + bb.z; o.w = acc[i][3] + bb.w;
            *(float4*)(O + n * DMODEL + col0 + tc) = o;
        }
    }
}

// ---------------------------------------------------------------------------
// Learned-RoPE rotation of Q and K, in place. One block per node.
// ---------------------------------------------------------------------------
__global__ __launch_bounds__(256) void rotate_qk(float* __restrict__ Q,
                                                 float* __restrict__ K,
                                                 const float* __restrict__ ang,
                                                 const float* __restrict__ P) {
    __shared__ float cbuf[HALF], sbuf[HALF];
    const int n = blockIdx.x;
    const int t = threadIdx.x;
    if (t < HALF) {
        float th = 0.f;
        #pragma unroll
        for (int a = 0; a < AA; ++a) th = fmaf(ang[n * AA + a], P[a * HALF + t], th);
        cbuf[t] = cosf(th);
        sbuf[t] = sinf(th);
    }
    __syncthreads();
    const int hd = t & 31;               // dim within head
    const int rowb = n * DMODEL;
    const int headb = t & ~31;           // head base within row
    const int pl = (hd < 16) ? (headb + 2 * hd + 1) : (headb + 2 * (hd - 16));
    const float sgn = (hd < 16) ? -1.f : 1.f;
    const float c = cbuf[t >> 1], s = sbuf[t >> 1];
    const float qv = Q[rowb + t], qp = Q[rowb + pl];
    const float kv = K[rowb + t], kp = K[rowb + pl];
    __syncthreads();   // all reads complete before in-place writes
    Q[rowb + t] = fmaf(qv, c, sgn * qp * s);
    K[rowb + t] = fmaf(kv, c, sgn * kp * s);
}

// ---------------------------------------------------------------------------
// CSR build step 1: histogram of destination nodes.
// ---------------------------------------------------------------------------
__global__ __launch_bounds__(256) void hist(const int* __restrict__ ei,
                                            int* __restrict__ cnt) {
    const unsigned e = blockIdx.x * 256u + threadIdx.x;
    if (e < EE) atomicAdd(&cnt[ei[EE + e]], 1);
}

// ---------------------------------------------------------------------------
// CSR build step 2: exclusive scan of cnt[NN] -> off[NN] (+ off[NN]=EE),
// and cursor[i] = off[i].  Single block, 1024 threads (16 waves).
// ---------------------------------------------------------------------------
__global__ __launch_bounds__(1024) void scan_offsets(const int* __restrict__ cnt,
                                                     int* __restrict__ off,
                                                     int* __restrict__ cursor) {
    __shared__ int wsum[16];
    __shared__ int chunk_base;
    const int t = threadIdx.x;
    const int wave = t >> 6, lane = t & 63;
    if (t == 0) chunk_base = 0;
    __syncthreads();
    for (int base = 0; base < NN; base += 1024) {
        const int i = base + t;
        const int v = (i < NN) ? cnt[i] : 0;
        // inclusive scan within wave
        int s = v;
        #pragma unroll
        for (int o = 1; o < 64; o <<= 1) {
            int u = __shfl_up(s, o);
            if (lane >= o) s += u;
        }
        if (lane == 63) wsum[wave] = s;
        __syncthreads();
        if (wave == 0 && lane < 16) {
            int ss = wsum[lane];
            #pragma unroll
            for (int o = 1; o < 16; o <<= 1) {
                int u = __shfl_up(ss, o);
                if (lane >= o) ss += u;
            }
            wsum[lane] = ss;   // inclusive scan of wave sums
        }
        __syncthreads();
        const int waveoff = (wave == 0) ? 0 : wsum[wave - 1];
        const int excl = chunk_base + waveoff + s - v;
        if (i < NN) { off[i] = excl; cursor[i] = excl; }
        __syncthreads();                    // all reads of chunk_base/wsum done
        if (t == 0) chunk_base += wsum[15];
        __syncthreads();
    }
    if (t == 0) off[NN] = EE;
}

// ---------------------------------------------------------------------------
// CSR build step 3: scatter src ids into dst buckets.
// ---------------------------------------------------------------------------
__global__ __launch_bounds__(256) void scatter(const int* __restrict__ ei,
                                               int* __restrict__ cursor,
                                               int* __restrict__ psrc) {
    const unsigned e = blockIdx.x * 256u + threadIdx.x;
    if (e < EE) {
        const int dst = ei[EE + e];
        const int pos = atomicAdd(&cursor[dst], 1);
        psrc[pos] = ei[e];
    }
}

// ---------------------------------------------------------------------------
// Fused per-destination attention: one WAVE per dst node.
// Lane r owns float4 at element 4r of the 256-wide row (head h = r>>3).
// For each edge in the dst's CSR bucket:
//   p = dot(K[src,h,:], Q[dst,h,:])  via 3-step shfl_xor in 8-lane groups
//   w = exp(clamp(p/sqrt(D), +-5))   (clamp makes max-free softmax exact ~1e-12)
//   acc += w * V[src]; wsum += w
// Finally out[dst] = acc / (wsum + eps).  Zero atomics, zero intermediates.
// ---------------------------------------------------------------------------
__global__ __launch_bounds__(256) void agg_csr(const float* __restrict__ Q,
                                               const float* __restrict__ K,
                                               const float* __restrict__ V,
                                               const int* __restrict__ off,
                                               const int* __restrict__ psrc,
                                               float* __restrict__ out) {
    const unsigned gid = blockIdx.x * 256u + threadIdx.x;   // exactly NN*64
    const int n = gid >> 6;
    const int r = gid & 63;
    const float4 q4 = *(const float4*)(Q + (size_t)n * DMODEL + r * 4);
    float4 acc = make_float4(0.f, 0.f, 0.f, 0.f);
    float wsum = 0.f;
    const int j0 = off[n], j1 = off[n + 1];
    for (int j = j0; j < j1; ++j) {
        const int src = psrc[j];
        const float4 k4 = *(const float4*)(K + (size_t)src * DMODEL + r * 4);
        float p = k4.x * q4.x;
        p = fmaf(k4.y, q4.y, p);
        p = fmaf(k4.z, q4.z, p);
        p = fmaf(k4.w, q4.w, p);
        p += __shfl_xor(p, 1);
        p += __shfl_xor(p, 2);
        p += __shfl_xor(p, 4);           // all 8 lanes of the head group hold the dot
        float sc = p * 0.17677669529663687f;    // 1/sqrt(32)
        sc = fminf(fmaxf(sc, -5.f), 5.f);
        const float wv = expf(sc);
        const float4 v4 = *(const float4*)(V + (size_t)src * DMODEL + r * 4);
        acc.x = fmaf(wv, v4.x, acc.x);
        acc.y = fmaf(wv, v4.y, acc.y);
        acc.z = fmaf(wv, v4.z, acc.z);
        acc.w = fmaf(wv, v4.w, acc.w);
        wsum += wv;
    }
    const float inv = 1.0f / (wsum + 1e-16f);
    float4 o;
    o.x = acc.x * inv; o.y = acc.y * inv; o.z = acc.z * inv; o.w = acc.w * inv;
    *(float4*)(out + (size_t)n * DMODEL + r * 4) = o;
}

// ---------------------------------------------------------------------------
extern "C" void kernel_launch(void* const* d_in, const int* in_sizes, int n_in,
                              void* d_out, int out_size, void* d_ws, size_t ws_size,
                              hipStream_t stream) {
    (void)in_sizes; (void)n_in; (void)out_size; (void)ws_size;
    const float* x    = (const float*)d_in[0];
    const float* ang  = (const float*)d_in[1];
    const int*   ei   = (const int*)d_in[2];
    const float* Wq   = (const float*)d_in[3];
    const float* bq   = (const float*)d_in[4];
    const float* Wk   = (const float*)d_in[5];
    const float* bk   = (const float*)d_in[6];
    const float* Wv   = (const float*)d_in[7];
    const float* bv   = (const float*)d_in[8];
    const float* S    = (const float*)d_in[9];
    float* out = (float*)d_out;
    float* ws  = (float*)d_ws;

    float* P = ws + P_OFF;
    float* Q = ws + Q_OFF;
    float* K = ws + K_OFF;
    float* V = ws + V_OFF;
    int* iws    = (int*)(ws + INT_OFF);
    int* cnt    = iws + CNT_I;
    int* off    = iws + OFF_I;
    int* cursor = iws + CUR_I;
    int* psrc   = iws + PSRC_I;

    // zero the histogram (d_ws is poisoned before every call)
    hipMemsetAsync(cnt, 0, (size_t)NN * sizeof(int), stream);

    softmax_S<<<1, 512, 0, stream>>>(S, P);

    dim3 ggrid((NN + 63) / 64, 12);
    qkv_gemm<<<ggrid, 256, 0, stream>>>(x, Wq, bq, Wk, bk, Wv, bv, Q, K, V);

    rotate_qk<<<NN, 256, 0, stream>>>(Q, K, ang, P);

    hist<<<(EE + 255) / 256, 256, 0, stream>>>(ei, cnt);
    scan_offsets<<<1, 1024, 0, stream>>>(cnt, off, cursor);
    scatter<<<(EE + 255) / 256, 256, 0, stream>>>(ei, cursor, psrc);

    agg_csr<<<(NN * 64) / 256, 256, 0, stream>>>(Q, K, V, off, psrc, out);
}

// Round 5
// 625.514 us; speedup vs baseline: 5.2981x; 1.2517x over previous
//
#include <hip/hip_runtime.h>
#include <math.h>

// Problem constants (match reference)
#define NN      50000
#define IND     256
#define HH      8
#define DD      32
#define DMODEL  256      // H*D
#define AA      8
#define EE      800000
#define HALF    128      // DMODEL/2

// Workspace layout (float-element offsets)
#define P_OFF    0                          // softmax(S): 8*128
#define Q_OFF    1024
#define K_OFF    (Q_OFF + NN*DMODEL)
#define V_OFF    (K_OFF + NN*DMODEL)
#define INT_OFF  (V_OFF + NN*DMODEL)        // int region starts here
// int-element offsets within the int region:
#define CNT_I    0                          // cnt[NN]
#define OFF_I    (CNT_I + NN)               // off[NN+1]
#define CUR_I    (OFF_I + NN + 1)           // cursor[NN]
#define PSRC_I   (CUR_I + NN)               // psrc[EE]
#define INT_TOTAL (PSRC_I + EE)             // 950001 ints
// bf16-split transposed weights Wt[768 cols][256 k], hi/lo (shorts)
#define WTH_OFF  (INT_OFF + INT_TOTAL + 3)  // float units (pad to alignment)
#define WTL_OFF  (WTH_OFF + (768*256)/2)    // 196608 shorts = 98304 float slots

typedef __attribute__((ext_vector_type(8))) short short8v;
typedef __attribute__((ext_vector_type(4))) float f32x4;

// RNE f32 -> bf16 bit split helpers
__device__ __forceinline__ short f2bf(float f) {
    union { float f; unsigned u; } v; v.f = f;
    unsigned r = v.u + 0x7fffu + ((v.u >> 16) & 1u);
    return (short)(r >> 16);
}
__device__ __forceinline__ float bf2f(short h) {
    union { unsigned u; float f; } v; v.u = ((unsigned)(unsigned short)h) << 16;
    return v.f;
}

// ---------------------------------------------------------------------------
// P = softmax(S, axis=1)   S:[8,128] -> one block, wave per row
// ---------------------------------------------------------------------------
__global__ __launch_bounds__(512) void softmax_S(const float* __restrict__ S,
                                                 float* __restrict__ P) {
    const int wave = threadIdx.x >> 6;   // row a = 0..7
    const int lane = threadIdx.x & 63;
    const float* row = S + wave * HALF;
    float s0 = row[lane], s1 = row[lane + 64];
    float m = fmaxf(s0, s1);
    #pragma unroll
    for (int off = 32; off; off >>= 1) m = fmaxf(m, __shfl_xor(m, off));
    float e0 = expf(s0 - m), e1 = expf(s1 - m);
    float sum = e0 + e1;
    #pragma unroll
    for (int off = 32; off; off >>= 1) sum += __shfl_xor(sum, off);
    float inv = 1.0f / sum;
    P[wave * HALF + lane]      = e0 * inv;
    P[wave * HALF + lane + 64] = e1 * inv;
}

// ---------------------------------------------------------------------------
// One-time: Wt_hi/Wt_lo[g=0..767][k=0..255] = bf16 split of W_m[k][c]
// (g = m*256 + c; transposed so GEMM B-frag reads are contiguous in k)
// ---------------------------------------------------------------------------
__global__ __launch_bounds__(256) void split_wt(const float* __restrict__ Wq,
                                                const float* __restrict__ Wk,
                                                const float* __restrict__ Wv,
                                                short* __restrict__ wt_hi,
                                                short* __restrict__ wt_lo) {
    const int g = blockIdx.x;      // output col 0..767
    const int k = threadIdx.x;     // 0..255
    const int m = g >> 8, c = g & 255;
    const float* W = (m == 0) ? Wq : (m == 1) ? Wk : Wv;
    const float v = W[k * 256 + c];
    const short hi = f2bf(v);
    wt_hi[g * 256 + k] = hi;
    wt_lo[g * 256 + k] = f2bf(v - bf2f(hi));
}

// ---------------------------------------------------------------------------
// QKV projection via split-bf16 MFMA (fp32-accurate):
//   C = x_hi@W_hi + x_lo@W_hi + x_hi@W_lo   (Alo*Blo term ~2^-18, dropped)
// Tile: BM=64 x BN=192, BK=32, 4 waves; wave w owns rows [w*16,w*16+16)
// x 192 cols = 12 mfma col-tiles. LDS rows padded to 40 shorts (80B pitch)
// -> ds_read_b128 frag reads are 2-way bank aliased (free, m136).
// mfma_f32_16x16x32_bf16: A lane: row=l&15,k=8*(l>>4)+j; B: col=l&15 same k;
// D: col=l&15, row=4*(l>>4)+reg (HW-verified m89/m91).
// ---------------------------------------------------------------------------
__global__ __launch_bounds__(256) void qkv_mfma(
    const float* __restrict__ x,
    const short* __restrict__ wt_hi, const short* __restrict__ wt_lo,
    const float* __restrict__ bq, const float* __restrict__ bk,
    const float* __restrict__ bv,
    float* __restrict__ Q, float* __restrict__ K, float* __restrict__ V) {
    __shared__ short Ahi[64 * 40], Alo[64 * 40];
    __shared__ short Bhi[192 * 40], Blo[192 * 40];
    const int t = threadIdx.x;
    const int w = t >> 6, l = t & 63;
    const int lr = l & 15, kg = l >> 4;
    const int n0 = blockIdx.x * 64;
    const int by = blockIdx.y;           // 0..3 (192-col slabs of 768)

    f32x4 zero = 0.0f;
    f32x4 acc[12];
    #pragma unroll
    for (int i = 0; i < 12; ++i) acc[i] = zero;

    const int arow = t >> 2;             // A-stage row 0..63
    const int ak8  = (t & 3) << 3;       // k-subgroup {0,8,16,24}
    const bool aok = (n0 + arow) < NN;
    const float* xrow = x + (size_t)(n0 + arow) * IND + ak8;
    const int bcol = t >> 2;             // B-stage col (per 64-col rep)

    for (int ks = 0; ks < 8; ++ks) {
        const int k0 = ks * 32;
        // ---- global -> regs (overlaps previous compute)
        float av[8];
        if (aok) {
            const float4 u0 = *(const float4*)(xrow + k0);
            const float4 u1 = *(const float4*)(xrow + k0 + 4);
            av[0] = u0.x; av[1] = u0.y; av[2] = u0.z; av[3] = u0.w;
            av[4] = u1.x; av[5] = u1.y; av[6] = u1.z; av[7] = u1.w;
        } else {
            #pragma unroll
            for (int i = 0; i < 8; ++i) av[i] = 0.f;
        }
        short8v ahi, alo;
        #pragma unroll
        for (int i = 0; i < 8; ++i) {
            const short h = f2bf(av[i]);
            ahi[i] = h;
            alo[i] = f2bf(av[i] - bf2f(h));
        }
        short8v bh[3], bl[3];
        #pragma unroll
        for (int rep = 0; rep < 3; ++rep) {
            const int g = by * 192 + rep * 64 + bcol;
            bh[rep] = *(const short8v*)&wt_hi[(size_t)g * 256 + k0 + ak8];
            bl[rep] = *(const short8v*)&wt_lo[(size_t)g * 256 + k0 + ak8];
        }
        __syncthreads();   // previous iteration's frag reads complete
        *(short8v*)&Ahi[arow * 40 + ak8] = ahi;
        *(short8v*)&Alo[arow * 40 + ak8] = alo;
        #pragma unroll
        for (int rep = 0; rep < 3; ++rep) {
            *(short8v*)&Bhi[(rep * 64 + bcol) * 40 + ak8] = bh[rep];
            *(short8v*)&Blo[(rep * 64 + bcol) * 40 + ak8] = bl[rep];
        }
        __syncthreads();
        const short8v a_hi = *(const short8v*)&Ahi[(w * 16 + lr) * 40 + kg * 8];
        const short8v a_lo = *(const short8v*)&Alo[(w * 16 + lr) * 40 + kg * 8];
        #pragma unroll
        for (int ct = 0; ct < 12; ++ct) {
            const short8v b_hi = *(const short8v*)&Bhi[(ct * 16 + lr) * 40 + kg * 8];
            const short8v b_lo = *(const short8v*)&Blo[(ct * 16 + lr) * 40 + kg * 8];
            acc[ct] = __builtin_amdgcn_mfma_f32_16x16x32_bf16(a_hi, b_hi, acc[ct], 0, 0, 0);
            acc[ct] = __builtin_amdgcn_mfma_f32_16x16x32_bf16(a_lo, b_hi, acc[ct], 0, 0, 0);
            acc[ct] = __builtin_amdgcn_mfma_f32_16x16x32_bf16(a_hi, b_lo, acc[ct], 0, 0, 0);
        }
    }
    // ---- epilogue: bias + store f32
    #pragma unroll
    for (int ct = 0; ct < 12; ++ct) {
        const int g = by * 192 + ct * 16 + lr;   // global col 0..767
        const int m = g >> 8, c = g & 255;       // matrix id, col within
        const float* bias = (m == 0) ? bq : (m == 1) ? bk : bv;
        float* O          = (m == 0) ? Q  : (m == 1) ? K  : V;
        const float bb = bias[c];
        #pragma unroll
        for (int r = 0; r < 4; ++r) {
            const int n = n0 + w * 16 + kg * 4 + r;
            if (n < NN) O[(size_t)n * 256 + c] = acc[ct][r] + bb;
        }
    }
}

// ---------------------------------------------------------------------------
// Learned-RoPE rotation of Q and K, in place. One block per node.
// ---------------------------------------------------------------------------
__global__ __launch_bounds__(256) void rotate_qk(float* __restrict__ Q,
                                                 float* __restrict__ K,
                                                 const float* __restrict__ ang,
                                                 const float* __restrict__ P) {
    __shared__ float cbuf[HALF], sbuf[HALF];
    const int n = blockIdx.x;
    const int t = threadIdx.x;
    if (t < HALF) {
        float th = 0.f;
        #pragma unroll
        for (int a = 0; a < AA; ++a) th = fmaf(ang[n * AA + a], P[a * HALF + t], th);
        cbuf[t] = cosf(th);
        sbuf[t] = sinf(th);
    }
    __syncthreads();
    const int hd = t & 31;               // dim within head
    const int rowb = n * DMODEL;
    const int headb = t & ~31;           // head base within row
    const int pl = (hd < 16) ? (headb + 2 * hd + 1) : (headb + 2 * (hd - 16));
    const float sgn = (hd < 16) ? -1.f : 1.f;
    const float c = cbuf[t >> 1], s = sbuf[t >> 1];
    const float qv = Q[rowb + t], qp = Q[rowb + pl];
    const float kv = K[rowb + t], kp = K[rowb + pl];
    __syncthreads();   // all reads complete before in-place writes
    Q[rowb + t] = fmaf(qv, c, sgn * qp * s);
    K[rowb + t] = fmaf(kv, c, sgn * kp * s);
}

// ---------------------------------------------------------------------------
// CSR build step 1: histogram of destination nodes.
// ---------------------------------------------------------------------------
__global__ __launch_bounds__(256) void hist(const int* __restrict__ ei,
                                            int* __restrict__ cnt) {
    const unsigned e = blockIdx.x * 256u + threadIdx.x;
    if (e < EE) atomicAdd(&cnt[ei[EE + e]], 1);
}

// ---------------------------------------------------------------------------
// CSR build step 2: exclusive scan of cnt[NN] -> off[NN] (+ off[NN]=EE),
// and cursor[i] = off[i].  Single block, 1024 threads (16 waves).
// ---------------------------------------------------------------------------
__global__ __launch_bounds__(1024) void scan_offsets(const int* __restrict__ cnt,
                                                     int* __restrict__ off,
                                                     int* __restrict__ cursor) {
    __shared__ int wsum[16];
    __shared__ int chunk_base;
    const int t = threadIdx.x;
    const int wave = t >> 6, lane = t & 63;
    if (t == 0) chunk_base = 0;
    __syncthreads();
    for (int base = 0; base < NN; base += 1024) {
        const int i = base + t;
        const int v = (i < NN) ? cnt[i] : 0;
        // inclusive scan within wave
        int s = v;
        #pragma unroll
        for (int o = 1; o < 64; o <<= 1) {
            int u = __shfl_up(s, o);
            if (lane >= o) s += u;
        }
        if (lane == 63) wsum[wave] = s;
        __syncthreads();
        if (wave == 0 && lane < 16) {
            int ss = wsum[lane];
            #pragma unroll
            for (int o = 1; o < 16; o <<= 1) {
                int u = __shfl_up(ss, o);
                if (lane >= o) ss += u;
            }
            wsum[lane] = ss;   // inclusive scan of wave sums
        }
        __syncthreads();
        const int waveoff = (wave == 0) ? 0 : wsum[wave - 1];
        const int excl = chunk_base + waveoff + s - v;
        if (i < NN) { off[i] = excl; cursor[i] = excl; }
        __syncthreads();                    // all reads of chunk_base/wsum done
        if (t == 0) chunk_base += wsum[15];
        __syncthreads();
    }
    if (t == 0) off[NN] = EE;
}

// ---------------------------------------------------------------------------
// CSR build step 3: scatter src ids into dst buckets.
// ---------------------------------------------------------------------------
__global__ __launch_bounds__(256) void scatter(const int* __restrict__ ei,
                                               int* __restrict__ cursor,
                                               int* __restrict__ psrc) {
    const unsigned e = blockIdx.x * 256u + threadIdx.x;
    if (e < EE) {
        const int dst = ei[EE + e];
        const int pos = atomicAdd(&cursor[dst], 1);
        psrc[pos] = ei[e];
    }
}

// ---------------------------------------------------------------------------
// Fused per-destination attention: one WAVE per dst node.
// ---------------------------------------------------------------------------
__global__ __launch_bounds__(256) void agg_csr(const float* __restrict__ Q,
                                               const float* __restrict__ K,
                                               const float* __restrict__ V,
                                               const int* __restrict__ off,
                                               const int* __restrict__ psrc,
                                               float* __restrict__ out) {
    const unsigned gid = blockIdx.x * 256u + threadIdx.x;   // exactly NN*64
    const int n = gid >> 6;
    const int r = gid & 63;
    const float4 q4 = *(const float4*)(Q + (size_t)n * DMODEL + r * 4);
    float4 acc = make_float4(0.f, 0.f, 0.f, 0.f);
    float wsum = 0.f;
    const int j0 = off[n], j1 = off[n + 1];
    for (int j = j0; j < j1; ++j) {
        const int src = psrc[j];
        const float4 k4 = *(const float4*)(K + (size_t)src * DMODEL + r * 4);
        float p = k4.x * q4.x;
        p = fmaf(k4.y, q4.y, p);
        p = fmaf(k4.z, q4.z, p);
        p = fmaf(k4.w, q4.w, p);
        p += __shfl_xor(p, 1);
        p += __shfl_xor(p, 2);
        p += __shfl_xor(p, 4);           // all 8 lanes of the head group hold the dot
        float sc = p * 0.17677669529663687f;    // 1/sqrt(32)
        sc = fminf(fmaxf(sc, -5.f), 5.f);
        const float wv = expf(sc);
        const float4 v4 = *(const float4*)(V + (size_t)src * DMODEL + r * 4);
        acc.x = fmaf(wv, v4.x, acc.x);
        acc.y = fmaf(wv, v4.y, acc.y);
        acc.z = fmaf(wv, v4.z, acc.z);
        acc.w = fmaf(wv, v4.w, acc.w);
        wsum += wv;
    }
    const float inv = 1.0f / (wsum + 1e-16f);
    float4 o;
    o.x = acc.x * inv; o.y = acc.y * inv; o.z = acc.z * inv; o.w = acc.w * inv;
    *(float4*)(out + (size_t)n * DMODEL + r * 4) = o;
}

// ---------------------------------------------------------------------------
extern "C" void kernel_launch(void* const* d_in, const int* in_sizes, int n_in,
                              void* d_out, int out_size, void* d_ws, size_t ws_size,
                              hipStream_t stream) {
    (void)in_sizes; (void)n_in; (void)out_size; (void)ws_size;
    const float* x    = (const float*)d_in[0];
    const float* ang  = (const float*)d_in[1];
    const int*   ei   = (const int*)d_in[2];
    const float* Wq   = (const float*)d_in[3];
    const float* bq   = (const float*)d_in[4];
    const float* Wk   = (const float*)d_in[5];
    const float* bk   = (const float*)d_in[6];
    const float* Wv   = (const float*)d_in[7];
    const float* bv   = (const float*)d_in[8];
    const float* S    = (const float*)d_in[9];
    float* out = (float*)d_out;
    float* ws  = (float*)d_ws;

    float* P = ws + P_OFF;
    float* Q = ws + Q_OFF;
    float* K = ws + K_OFF;
    float* V = ws + V_OFF;
    int* iws    = (int*)(ws + INT_OFF);
    int* cnt    = iws + CNT_I;
    int* off    = iws + OFF_I;
    int* cursor = iws + CUR_I;
    int* psrc   = iws + PSRC_I;
    short* wt_hi = (short*)(ws + WTH_OFF);
    short* wt_lo = (short*)(ws + WTL_OFF);

    // zero the histogram (d_ws is poisoned before every call)
    hipMemsetAsync(cnt, 0, (size_t)NN * sizeof(int), stream);

    softmax_S<<<1, 512, 0, stream>>>(S, P);

    split_wt<<<768, 256, 0, stream>>>(Wq, Wk, Wv, wt_hi, wt_lo);

    dim3 ggrid((NN + 63) / 64, 4);
    qkv_mfma<<<ggrid, 256, 0, stream>>>(x, wt_hi, wt_lo, bq, bk, bv, Q, K, V);

    rotate_qk<<<NN, 256, 0, stream>>>(Q, K, ang, P);

    hist<<<(EE + 255) / 256, 256, 0, stream>>>(ei, cnt);
    scan_offsets<<<1, 1024, 0, stream>>>(cnt, off, cursor);
    scatter<<<(EE + 255) / 256, 256, 0, stream>>>(ei, cursor, psrc);

    agg_csr<<<(NN * 64) / 256, 256, 0, stream>>>(Q, K, V, off, psrc, out);
}

// Round 8
// 568.908 us; speedup vs baseline: 5.8252x; 1.0995x over previous
//
#include <hip/hip_runtime.h>
#include <math.h>

// Problem constants (match reference)
#define NN      50000
#define IND     256
#define HH      8
#define DD      32
#define DMODEL  256      // H*D
#define AA      8
#define EE      800000
#define HALF    128      // DMODEL/2

// Workspace layout (float-element offsets)
#define P_OFF    0                          // softmax(S): 8*128
#define QB_OFF   1024                       // Qb: NN*256 ushorts = 6.4M float slots
#define KB_OFF   (QB_OFF + NN*DMODEL/2)     // Kb: NN*256 ushorts
#define V_OFF    (KB_OFF + NN*DMODEL/2)     // V : NN*256 floats
#define INT_OFF  (V_OFF + NN*DMODEL)        // int region starts here
// int-element offsets within the int region:
#define CNT_I    0                          // cnt[NN]
#define OFF_I    (CNT_I + NN)               // off[NN+1]
#define CUR_I    (OFF_I + NN + 1)           // cursor[NN]
#define PSRC_I   (CUR_I + NN)               // psrc[EE]
#define INT_TOTAL (PSRC_I + EE)             // 950001 ints
// bf16-split transposed weights Wt[768 cols][256 k], hi/lo (shorts)
#define WTH_OFF  (INT_OFF + INT_TOTAL + 3)  // float units (pad to alignment)
#define WTL_OFF  (WTH_OFF + (768*256)/2)    // 196608 shorts = 98304 float slots

typedef __attribute__((ext_vector_type(8))) short short8v;
typedef __attribute__((ext_vector_type(4))) float f32x4;

// RNE f32 -> bf16 bit helpers
__device__ __forceinline__ unsigned short f2bf(float f) {
    union { float f; unsigned u; } v; v.f = f;
    unsigned r = v.u + 0x7fffu + ((v.u >> 16) & 1u);
    return (unsigned short)(r >> 16);
}
__device__ __forceinline__ float bf2f(unsigned short h) {
    union { unsigned u; float f; } v; v.u = ((unsigned)h) << 16;
    return v.f;
}

// ---------------------------------------------------------------------------
// P = softmax(S, axis=1)   S:[8,128] -> one block, wave per row
// ---------------------------------------------------------------------------
__global__ __launch_bounds__(512) void softmax_S(const float* __restrict__ S,
                                                 float* __restrict__ P) {
    const int wave = threadIdx.x >> 6;   // row a = 0..7
    const int lane = threadIdx.x & 63;
    const float* row = S + wave * HALF;
    float s0 = row[lane], s1 = row[lane + 64];
    float m = fmaxf(s0, s1);
    #pragma unroll
    for (int off = 32; off; off >>= 1) m = fmaxf(m, __shfl_xor(m, off));
    float e0 = expf(s0 - m), e1 = expf(s1 - m);
    float sum = e0 + e1;
    #pragma unroll
    for (int off = 32; off; off >>= 1) sum += __shfl_xor(sum, off);
    float inv = 1.0f / sum;
    P[wave * HALF + lane]      = e0 * inv;
    P[wave * HALF + lane + 64] = e1 * inv;
}

// ---------------------------------------------------------------------------
// One-time: Wt_hi/Wt_lo[g=0..767][k=0..255] = bf16 split of W_m[k][c]
// ---------------------------------------------------------------------------
__global__ __launch_bounds__(256) void split_wt(const float* __restrict__ Wq,
                                                const float* __restrict__ Wk,
                                                const float* __restrict__ Wv,
                                                short* __restrict__ wt_hi,
                                                short* __restrict__ wt_lo) {
    const int g = blockIdx.x;      // output col 0..767
    const int k = threadIdx.x;     // 0..255
    const int m = g >> 8, c = g & 255;
    const float* W = (m == 0) ? Wq : (m == 1) ? Wk : Wv;
    const float v = W[k * 256 + c];
    const unsigned short hi = f2bf(v);
    wt_hi[g * 256 + k] = (short)hi;
    wt_lo[g * 256 + k] = (short)f2bf(v - bf2f(hi));
}

// ---------------------------------------------------------------------------
// QKV projection via split-bf16 MFMA (fp32-accurate):
//   C = x_hi@W_hi + x_lo@W_hi + x_hi@W_lo   (Alo*Blo term ~2^-18, dropped)
// Tile: BM=64 x BN=192, BK=32, 4 waves. Q,K stored bf16; V stored f32.
// ---------------------------------------------------------------------------
__global__ __launch_bounds__(256) void qkv_mfma(
    const float* __restrict__ x,
    const short* __restrict__ wt_hi, const short* __restrict__ wt_lo,
    const float* __restrict__ bq, const float* __restrict__ bk,
    const float* __restrict__ bv,
    unsigned short* __restrict__ Qb, unsigned short* __restrict__ Kb,
    float* __restrict__ V) {
    __shared__ short Ahi[64 * 40], Alo[64 * 40];
    __shared__ short Bhi[192 * 40], Blo[192 * 40];
    const int t = threadIdx.x;
    const int w = t >> 6, l = t & 63;
    const int lr = l & 15, kg = l >> 4;
    const int n0 = blockIdx.x * 64;
    const int by = blockIdx.y;           // 0..3 (192-col slabs of 768)

    f32x4 zero = 0.0f;
    f32x4 acc[12];
    #pragma unroll
    for (int i = 0; i < 12; ++i) acc[i] = zero;

    const int arow = t >> 2;             // A-stage row 0..63
    const int ak8  = (t & 3) << 3;       // k-subgroup {0,8,16,24}
    const bool aok = (n0 + arow) < NN;
    const float* xrow = x + (size_t)(n0 + arow) * IND + ak8;
    const int bcol = t >> 2;             // B-stage col (per 64-col rep)

    for (int ks = 0; ks < 8; ++ks) {
        const int k0 = ks * 32;
        float av[8];
        if (aok) {
            const float4 u0 = *(const float4*)(xrow + k0);
            const float4 u1 = *(const float4*)(xrow + k0 + 4);
            av[0] = u0.x; av[1] = u0.y; av[2] = u0.z; av[3] = u0.w;
            av[4] = u1.x; av[5] = u1.y; av[6] = u1.z; av[7] = u1.w;
        } else {
            #pragma unroll
            for (int i = 0; i < 8; ++i) av[i] = 0.f;
        }
        short8v ahi, alo;
        #pragma unroll
        for (int i = 0; i < 8; ++i) {
            const unsigned short h = f2bf(av[i]);
            ahi[i] = (short)h;
            alo[i] = (short)f2bf(av[i] - bf2f(h));
        }
        short8v bh[3], bl[3];
        #pragma unroll
        for (int rep = 0; rep < 3; ++rep) {
            const int g = by * 192 + rep * 64 + bcol;
            bh[rep] = *(const short8v*)&wt_hi[(size_t)g * 256 + k0 + ak8];
            bl[rep] = *(const short8v*)&wt_lo[(size_t)g * 256 + k0 + ak8];
        }
        __syncthreads();   // previous iteration's frag reads complete
        *(short8v*)&Ahi[arow * 40 + ak8] = ahi;
        *(short8v*)&Alo[arow * 40 + ak8] = alo;
        #pragma unroll
        for (int rep = 0; rep < 3; ++rep) {
            *(short8v*)&Bhi[(rep * 64 + bcol) * 40 + ak8] = bh[rep];
            *(short8v*)&Blo[(rep * 64 + bcol) * 40 + ak8] = bl[rep];
        }
        __syncthreads();
        const short8v a_hi = *(const short8v*)&Ahi[(w * 16 + lr) * 40 + kg * 8];
        const short8v a_lo = *(const short8v*)&Alo[(w * 16 + lr) * 40 + kg * 8];
        #pragma unroll
        for (int ct = 0; ct < 12; ++ct) {
            const short8v b_hi = *(const short8v*)&Bhi[(ct * 16 + lr) * 40 + kg * 8];
            const short8v b_lo = *(const short8v*)&Blo[(ct * 16 + lr) * 40 + kg * 8];
            acc[ct] = __builtin_amdgcn_mfma_f32_16x16x32_bf16(a_hi, b_hi, acc[ct], 0, 0, 0);
            acc[ct] = __builtin_amdgcn_mfma_f32_16x16x32_bf16(a_lo, b_hi, acc[ct], 0, 0, 0);
            acc[ct] = __builtin_amdgcn_mfma_f32_16x16x32_bf16(a_hi, b_lo, acc[ct], 0, 0, 0);
        }
    }
    // ---- epilogue: bias + store (Q,K -> bf16; V -> f32)
    #pragma unroll
    for (int ct = 0; ct < 12; ++ct) {
        const int g = by * 192 + ct * 16 + lr;   // global col 0..767
        const int m = g >> 8, c = g & 255;       // matrix id, col within
        const float bb = ((m == 0) ? bq : (m == 1) ? bk : bv)[c];
        #pragma unroll
        for (int r = 0; r < 4; ++r) {
            const int n = n0 + w * 16 + kg * 4 + r;
            if (n < NN) {
                const float val = acc[ct][r] + bb;
                if (m == 0)      Qb[(size_t)n * 256 + c] = f2bf(val);
                else if (m == 1) Kb[(size_t)n * 256 + c] = f2bf(val);
                else             V [(size_t)n * 256 + c] = val;
            }
        }
    }
}

// ---------------------------------------------------------------------------
// Learned-RoPE rotation of Q and K (bf16 in place). One block per node.
// ---------------------------------------------------------------------------
__global__ __launch_bounds__(256) void rotate_qk(unsigned short* __restrict__ Qb,
                                                 unsigned short* __restrict__ Kb,
                                                 const float* __restrict__ ang,
                                                 const float* __restrict__ P) {
    __shared__ float cbuf[HALF], sbuf[HALF];
    const int n = blockIdx.x;
    const int t = threadIdx.x;
    if (t < HALF) {
        float th = 0.f;
        #pragma unroll
        for (int a = 0; a < AA; ++a) th = fmaf(ang[n * AA + a], P[a * HALF + t], th);
        cbuf[t] = cosf(th);
        sbuf[t] = sinf(th);
    }
    __syncthreads();
    const int hd = t & 31;               // dim within head
    const int rowb = n * DMODEL;
    const int headb = t & ~31;           // head base within row
    const int pl = (hd < 16) ? (headb + 2 * hd + 1) : (headb + 2 * (hd - 16));
    const float sgn = (hd < 16) ? -1.f : 1.f;
    const float c = cbuf[t >> 1], s = sbuf[t >> 1];
    const float qv = bf2f(Qb[rowb + t]), qp = bf2f(Qb[rowb + pl]);
    const float kv = bf2f(Kb[rowb + t]), kp = bf2f(Kb[rowb + pl]);
    __syncthreads();   // all reads complete before in-place writes
    Qb[rowb + t] = f2bf(fmaf(qv, c, sgn * qp * s));
    Kb[rowb + t] = f2bf(fmaf(kv, c, sgn * kp * s));
}

// ---------------------------------------------------------------------------
// CSR build step 1: histogram of destination nodes.
// ---------------------------------------------------------------------------
__global__ __launch_bounds__(256) void hist(const int* __restrict__ ei,
                                            int* __restrict__ cnt) {
    const unsigned e = blockIdx.x * 256u + threadIdx.x;
    if (e < EE) atomicAdd(&cnt[ei[EE + e]], 1);
}

// ---------------------------------------------------------------------------
// CSR build step 2: exclusive scan of cnt[NN] -> off[NN] (+ off[NN]=EE),
// and cursor[i] = off[i].  Single block, 1024 threads (16 waves).
// ---------------------------------------------------------------------------
__global__ __launch_bounds__(1024) void scan_offsets(const int* __restrict__ cnt,
                                                     int* __restrict__ off,
                                                     int* __restrict__ cursor) {
    __shared__ int wsum[16];
    __shared__ int chunk_base;
    const int t = threadIdx.x;
    const int wave = t >> 6, lane = t & 63;
    if (t == 0) chunk_base = 0;
    __syncthreads();
    for (int base = 0; base < NN; base += 1024) {
        const int i = base + t;
        const int v = (i < NN) ? cnt[i] : 0;
        int s = v;
        #pragma unroll
        for (int o = 1; o < 64; o <<= 1) {
            int u = __shfl_up(s, o);
            if (lane >= o) s += u;
        }
        if (lane == 63) wsum[wave] = s;
        __syncthreads();
        if (wave == 0 && lane < 16) {
            int ss = wsum[lane];
            #pragma unroll
            for (int o = 1; o < 16; o <<= 1) {
                int u = __shfl_up(ss, o);
                if (lane >= o) ss += u;
            }
            wsum[lane] = ss;
        }
        __syncthreads();
        const int waveoff = (wave == 0) ? 0 : wsum[wave - 1];
        const int excl = chunk_base + waveoff + s - v;
        if (i < NN) { off[i] = excl; cursor[i] = excl; }
        __syncthreads();
        if (t == 0) chunk_base += wsum[15];
        __syncthreads();
    }
    if (t == 0) off[NN] = EE;
}

// ---------------------------------------------------------------------------
// CSR build step 3: scatter src ids into dst buckets.
// ---------------------------------------------------------------------------
__global__ __launch_bounds__(256) void scatter(const int* __restrict__ ei,
                                               int* __restrict__ cursor,
                                               int* __restrict__ psrc) {
    const unsigned e = blockIdx.x * 256u + threadIdx.x;
    if (e < EE) {
        const int dst = ei[EE + e];
        const int pos = atomicAdd(&cursor[dst], 1);
        psrc[pos] = ei[e];
    }
}

// ---------------------------------------------------------------------------
// Fused per-destination attention: one WAVE per dst node.
// Q,K gathered as bf16 (512B/row); V fp32. psrc read in coalesced 64-chunks
// and broadcast via shfl. Scores use max-free softmax (clamp +-5, ~1e-12).
// ---------------------------------------------------------------------------
__global__ __launch_bounds__(256) void agg_csr(const unsigned short* __restrict__ Qb,
                                               const unsigned short* __restrict__ Kb,
                                               const float* __restrict__ V,
                                               const int* __restrict__ off,
                                               const int* __restrict__ psrc,
                                               float* __restrict__ out) {
    const unsigned gid = blockIdx.x * 256u + threadIdx.x;   // exactly NN*64
    const int n = gid >> 6;
    const int r = gid & 63;
    const ushort4 qu = *(const ushort4*)(Qb + (size_t)n * DMODEL + r * 4);
    const float qs = 0.17677669529663687f;   // 1/sqrt(32) folded into Q
    const float qx = bf2f(qu.x) * qs, qy = bf2f(qu.y) * qs;
    const float qz = bf2f(qu.z) * qs, qw = bf2f(qu.w) * qs;
    float4 acc = make_float4(0.f, 0.f, 0.f, 0.f);
    float wsum = 0.f;
    const int j0 = off[n], j1 = off[n + 1];
    for (int base = j0; base < j1; base += 64) {
        const int m = j1 - base < 64 ? j1 - base : 64;
        const int sv = (base + r < j1) ? psrc[base + r] : 0;
        for (int i = 0; i < m; ++i) {
            const int src = __shfl(sv, i);
            const ushort4 ku = *(const ushort4*)(Kb + (size_t)src * DMODEL + r * 4);
            float p = bf2f(ku.x) * qx;
            p = fmaf(bf2f(ku.y), qy, p);
            p = fmaf(bf2f(ku.z), qz, p);
            p = fmaf(bf2f(ku.w), qw, p);
            p += __shfl_xor(p, 1);
            p += __shfl_xor(p, 2);
            p += __shfl_xor(p, 4);       // 8-lane head group holds the dot
            float sc = fminf(fmaxf(p, -5.f), 5.f);
            const float wv = expf(sc);
            const float4 v4 = *(const float4*)(V + (size_t)src * DMODEL + r * 4);
            acc.x = fmaf(wv, v4.x, acc.x);
            acc.y = fmaf(wv, v4.y, acc.y);
            acc.z = fmaf(wv, v4.z, acc.z);
            acc.w = fmaf(wv, v4.w, acc.w);
            wsum += wv;
        }
    }
    const float inv = 1.0f / (wsum + 1e-16f);
    float4 o;
    o.x = acc.x * inv; o.y = acc.y * inv; o.z = acc.z * inv; o.w = acc.w * inv;
    *(float4*)(out + (size_t)n * DMODEL + r * 4) = o;
}

// ---------------------------------------------------------------------------
extern "C" void kernel_launch(void* const* d_in, const int* in_sizes, int n_in,
                              void* d_out, int out_size, void* d_ws, size_t ws_size,
                              hipStream_t stream) {
    (void)in_sizes; (void)n_in; (void)out_size; (void)ws_size;
    const float* x    = (const float*)d_in[0];
    const float* ang  = (const float*)d_in[1];
    const int*   ei   = (const int*)d_in[2];
    const float* Wq   = (const float*)d_in[3];
    const float* bq   = (const float*)d_in[4];
    const float* Wk   = (const float*)d_in[5];
    const float* bk   = (const float*)d_in[6];
    const float* Wv   = (const float*)d_in[7];
    const float* bv   = (const float*)d_in[8];
    const float* S    = (const float*)d_in[9];
    float* out = (float*)d_out;
    float* ws  = (float*)d_ws;

    float* P = ws + P_OFF;
    unsigned short* Qb = (unsigned short*)(ws + QB_OFF);
    unsigned short* Kb = (unsigned short*)(ws + KB_OFF);
    float* V = ws + V_OFF;
    int* iws    = (int*)(ws + INT_OFF);
    int* cnt    = iws + CNT_I;
    int* off    = iws + OFF_I;
    int* cursor = iws + CUR_I;
    int* psrc   = iws + PSRC_I;
    short* wt_hi = (short*)(ws + WTH_OFF);
    short* wt_lo = (short*)(ws + WTL_OFF);

    // zero the histogram (d_ws is poisoned before every call)
    hipMemsetAsync(cnt, 0, (size_t)NN * sizeof(int), stream);

    softmax_S<<<1, 512, 0, stream>>>(S, P);

    split_wt<<<768, 256, 0, stream>>>(Wq, Wk, Wv, wt_hi, wt_lo);

    dim3 ggrid((NN + 63) / 64, 4);
    qkv_mfma<<<ggrid, 256, 0, stream>>>(x, wt_hi, wt_lo, bq, bk, bv, Qb, Kb, V);

    rotate_qk<<<NN, 256, 0, stream>>>(Qb, Kb, ang, P);

    hist<<<(EE + 255) / 256, 256, 0, stream>>>(ei, cnt);
    scan_offsets<<<1, 1024, 0, stream>>>(cnt, off, cursor);
    scatter<<<(EE + 255) / 256, 256, 0, stream>>>(ei, cursor, psrc);

    agg_csr<<<(NN * 64) / 256, 256, 0, stream>>>(Qb, Kb, V, off, psrc, out);
}

// Round 16
// 494.923 us; speedup vs baseline: 6.6960x; 1.1495x over previous
//
#include <hip/hip_runtime.h>
#include <math.h>

// Problem constants (match reference)
#define NN      50000
#define IND     256
#define HH      8
#define DD      32
#define DMODEL  256      // H*D
#define AA      8
#define EE      800000
#define HALF    128      // DMODEL/2

// Workspace layout (float-element offsets)
#define P_OFF    0                          // softmax(S): 8*128
#define QB_OFF   1024                       // Qb: NN*256 ushorts
#define KB_OFF   (QB_OFF + NN*DMODEL/2)     // Kb: NN*256 ushorts
#define V_OFF    (KB_OFF + NN*DMODEL/2)     // Vb: NN*256 ushorts (region kept fp32-sized)
#define INT_OFF  (V_OFF + NN*DMODEL)        // int region starts here (unchanged)
// int-element offsets within the int region:
#define CNT_I    0                          // cnt[NN]
#define OFF_I    (CNT_I + NN)               // off[NN+1]
#define CUR_I    (OFF_I + NN + 1)           // cursor[NN]
#define PSRC_I   (CUR_I + NN)               // psrc[EE]
#define INT_TOTAL (PSRC_I + EE)             // 950001 ints
// bf16-split transposed weights Wt[768 cols][256 k], hi/lo (shorts)
#define WTH_OFF  (INT_OFF + INT_TOTAL + 3)  // float units (pad to alignment)
#define WTL_OFF  (WTH_OFF + (768*256)/2)    // 196608 shorts = 98304 float slots

typedef __attribute__((ext_vector_type(8))) short short8v;
typedef __attribute__((ext_vector_type(8))) unsigned short us8v;
typedef __attribute__((ext_vector_type(4))) float f32x4;

// RNE f32 -> bf16 bit helpers
__device__ __forceinline__ unsigned short f2bf(float f) {
    union { float f; unsigned u; } v; v.f = f;
    unsigned r = v.u + 0x7fffu + ((v.u >> 16) & 1u);
    return (unsigned short)(r >> 16);
}
__device__ __forceinline__ float bf2f(unsigned short h) {
    union { unsigned u; float f; } v; v.u = ((unsigned)h) << 16;
    return v.f;
}

// ---------------------------------------------------------------------------
// P = softmax(S, axis=1)   S:[8,128] -> one block, wave per row
// ---------------------------------------------------------------------------
__global__ __launch_bounds__(512) void softmax_S(const float* __restrict__ S,
                                                 float* __restrict__ P) {
    const int wave = threadIdx.x >> 6;   // row a = 0..7
    const int lane = threadIdx.x & 63;
    const float* row = S + wave * HALF;
    float s0 = row[lane], s1 = row[lane + 64];
    float m = fmaxf(s0, s1);
    #pragma unroll
    for (int off = 32; off; off >>= 1) m = fmaxf(m, __shfl_xor(m, off));
    float e0 = expf(s0 - m), e1 = expf(s1 - m);
    float sum = e0 + e1;
    #pragma unroll
    for (int off = 32; off; off >>= 1) sum += __shfl_xor(sum, off);
    float inv = 1.0f / sum;
    P[wave * HALF + lane]      = e0 * inv;
    P[wave * HALF + lane + 64] = e1 * inv;
}

// ---------------------------------------------------------------------------
// One-time: Wt_hi/Wt_lo[g=0..767][k=0..255] = bf16 split of W_m[k][c]
// ---------------------------------------------------------------------------
__global__ __launch_bounds__(256) void split_wt(const float* __restrict__ Wq,
                                                const float* __restrict__ Wk,
                                                const float* __restrict__ Wv,
                                                short* __restrict__ wt_hi,
                                                short* __restrict__ wt_lo) {
    const int g = blockIdx.x;      // output col 0..767
    const int k = threadIdx.x;     // 0..255
    const int m = g >> 8, c = g & 255;
    const float* W = (m == 0) ? Wq : (m == 1) ? Wk : Wv;
    const float v = W[k * 256 + c];
    const unsigned short hi = f2bf(v);
    wt_hi[g * 256 + k] = (short)hi;
    wt_lo[g * 256 + k] = (short)f2bf(v - bf2f(hi));
}

// ---------------------------------------------------------------------------
// QKV projection via split-bf16 MFMA (fp32-accurate):
//   C = x_hi@W_hi + x_lo@W_hi + x_hi@W_lo   (Alo*Blo term ~2^-18, dropped)
// Tile: BM=64 x BN=192, BK=32, 4 waves. Q,K,V all stored bf16.
// ---------------------------------------------------------------------------
__global__ __launch_bounds__(256) void qkv_mfma(
    const float* __restrict__ x,
    const short* __restrict__ wt_hi, const short* __restrict__ wt_lo,
    const float* __restrict__ bq, const float* __restrict__ bk,
    const float* __restrict__ bv,
    unsigned short* __restrict__ Qb, unsigned short* __restrict__ Kb,
    unsigned short* __restrict__ Vb) {
    __shared__ short Ahi[64 * 40], Alo[64 * 40];
    __shared__ short Bhi[192 * 40], Blo[192 * 40];
    const int t = threadIdx.x;
    const int w = t >> 6, l = t & 63;
    const int lr = l & 15, kg = l >> 4;
    const int n0 = blockIdx.x * 64;
    const int by = blockIdx.y;           // 0..3 (192-col slabs of 768)

    f32x4 zero = 0.0f;
    f32x4 acc[12];
    #pragma unroll
    for (int i = 0; i < 12; ++i) acc[i] = zero;

    const int arow = t >> 2;             // A-stage row 0..63
    const int ak8  = (t & 3) << 3;       // k-subgroup {0,8,16,24}
    const bool aok = (n0 + arow) < NN;
    const float* xrow = x + (size_t)(n0 + arow) * IND + ak8;
    const int bcol = t >> 2;             // B-stage col (per 64-col rep)

    for (int ks = 0; ks < 8; ++ks) {
        const int k0 = ks * 32;
        float av[8];
        if (aok) {
            const float4 u0 = *(const float4*)(xrow + k0);
            const float4 u1 = *(const float4*)(xrow + k0 + 4);
            av[0] = u0.x; av[1] = u0.y; av[2] = u0.z; av[3] = u0.w;
            av[4] = u1.x; av[5] = u1.y; av[6] = u1.z; av[7] = u1.w;
        } else {
            #pragma unroll
            for (int i = 0; i < 8; ++i) av[i] = 0.f;
        }
        short8v ahi, alo;
        #pragma unroll
        for (int i = 0; i < 8; ++i) {
            const unsigned short h = f2bf(av[i]);
            ahi[i] = (short)h;
            alo[i] = (short)f2bf(av[i] - bf2f(h));
        }
        short8v bh[3], bl[3];
        #pragma unroll
        for (int rep = 0; rep < 3; ++rep) {
            const int g = by * 192 + rep * 64 + bcol;
            bh[rep] = *(const short8v*)&wt_hi[(size_t)g * 256 + k0 + ak8];
            bl[rep] = *(const short8v*)&wt_lo[(size_t)g * 256 + k0 + ak8];
        }
        __syncthreads();   // previous iteration's frag reads complete
        *(short8v*)&Ahi[arow * 40 + ak8] = ahi;
        *(short8v*)&Alo[arow * 40 + ak8] = alo;
        #pragma unroll
        for (int rep = 0; rep < 3; ++rep) {
            *(short8v*)&Bhi[(rep * 64 + bcol) * 40 + ak8] = bh[rep];
            *(short8v*)&Blo[(rep * 64 + bcol) * 40 + ak8] = bl[rep];
        }
        __syncthreads();
        const short8v a_hi = *(const short8v*)&Ahi[(w * 16 + lr) * 40 + kg * 8];
        const short8v a_lo = *(const short8v*)&Alo[(w * 16 + lr) * 40 + kg * 8];
        #pragma unroll
        for (int ct = 0; ct < 12; ++ct) {
            const short8v b_hi = *(const short8v*)&Bhi[(ct * 16 + lr) * 40 + kg * 8];
            const short8v b_lo = *(const short8v*)&Blo[(ct * 16 + lr) * 40 + kg * 8];
            acc[ct] = __builtin_amdgcn_mfma_f32_16x16x32_bf16(a_hi, b_hi, acc[ct], 0, 0, 0);
            acc[ct] = __builtin_amdgcn_mfma_f32_16x16x32_bf16(a_lo, b_hi, acc[ct], 0, 0, 0);
            acc[ct] = __builtin_amdgcn_mfma_f32_16x16x32_bf16(a_hi, b_lo, acc[ct], 0, 0, 0);
        }
    }
    // ---- epilogue: bias + store (all bf16)
    #pragma unroll
    for (int ct = 0; ct < 12; ++ct) {
        const int g = by * 192 + ct * 16 + lr;   // global col 0..767
        const int m = g >> 8, c = g & 255;       // matrix id, col within
        const float bb = ((m == 0) ? bq : (m == 1) ? bk : bv)[c];
        unsigned short* O = (m == 0) ? Qb : (m == 1) ? Kb : Vb;
        #pragma unroll
        for (int r = 0; r < 4; ++r) {
            const int n = n0 + w * 16 + kg * 4 + r;
            if (n < NN) O[(size_t)n * 256 + c] = f2bf(acc[ct][r] + bb);
        }
    }
}

// ---------------------------------------------------------------------------
// Learned-RoPE rotation, register-local: one THREAD per (node, head).
// A head's 32 elements pair only within the head (d<16 with 2d+1; d>=16 with
// 2(d-16)), so the whole rotation is thread-local: 4x16B vector loads per
// matrix, no LDS, no sync. theta[j] = sum_a ang[n,a]*P[a][h*16+j];
// out[hd] = in[hd]*cos(th[hd>>1]) + sgn*in[partner]*sin(th[hd>>1]).
// ---------------------------------------------------------------------------
__global__ __launch_bounds__(256) void rotate_qk(unsigned short* __restrict__ Qb,
                                                 unsigned short* __restrict__ Kb,
                                                 const float* __restrict__ ang,
                                                 const float* __restrict__ P) {
    const int t = threadIdx.x;
    const int n = blockIdx.x * 32 + (t >> 3);
    if (n >= NN) return;
    const int h = t & 7;
    const size_t base = (size_t)n * DMODEL + h * 32;

    us8v qv[4], kv[4];
    #pragma unroll
    for (int i = 0; i < 4; ++i) {
        qv[i] = *(const us8v*)(Qb + base + i * 8);
        kv[i] = *(const us8v*)(Kb + base + i * 8);
    }
    float av[AA];
    #pragma unroll
    for (int a = 0; a < AA; ++a) av[a] = ang[n * AA + a];

    float th[16];
    #pragma unroll
    for (int j = 0; j < 16; ++j) th[j] = 0.f;
    #pragma unroll
    for (int a = 0; a < AA; ++a) {
        const float aa = av[a];
        const float* Pr = P + a * HALF + h * 16;
        #pragma unroll
        for (int j4 = 0; j4 < 4; ++j4) {
            const float4 p4 = *(const float4*)(Pr + j4 * 4);
            th[j4 * 4 + 0] = fmaf(aa, p4.x, th[j4 * 4 + 0]);
            th[j4 * 4 + 1] = fmaf(aa, p4.y, th[j4 * 4 + 1]);
            th[j4 * 4 + 2] = fmaf(aa, p4.z, th[j4 * 4 + 2]);
            th[j4 * 4 + 3] = fmaf(aa, p4.w, th[j4 * 4 + 3]);
        }
    }
    float cth[16], sth[16];
    #pragma unroll
    for (int j = 0; j < 16; ++j) { cth[j] = cosf(th[j]); sth[j] = sinf(th[j]); }

    float q[32], k[32];
    #pragma unroll
    for (int i = 0; i < 4; ++i) {
        #pragma unroll
        for (int j = 0; j < 8; ++j) {
            q[i * 8 + j] = bf2f(qv[i][j]);
            k[i * 8 + j] = bf2f(kv[i][j]);
        }
    }
    us8v qo[4], ko[4];
    #pragma unroll
    for (int hd = 0; hd < 32; ++hd) {
        const float c = cth[hd >> 1], s = sth[hd >> 1];
        float qr, kr;
        if (hd < 16) { qr = -q[2 * hd + 1];    kr = -k[2 * hd + 1]; }
        else         { qr =  q[2 * (hd - 16)]; kr =  k[2 * (hd - 16)]; }
        qo[hd >> 3][hd & 7] = f2bf(fmaf(q[hd], c, qr * s));
        ko[hd >> 3][hd & 7] = f2bf(fmaf(k[hd], c, kr * s));
    }
    #pragma unroll
    for (int i = 0; i < 4; ++i) {
        *(us8v*)(Qb + base + i * 8) = qo[i];
        *(us8v*)(Kb + base + i * 8) = ko[i];
    }
}

// ---------------------------------------------------------------------------
// CSR build step 1: histogram of destination nodes.
// ---------------------------------------------------------------------------
__global__ __launch_bounds__(256) void hist(const int* __restrict__ ei,
                                            int* __restrict__ cnt) {
    const unsigned e = blockIdx.x * 256u + threadIdx.x;
    if (e < EE) atomicAdd(&cnt[ei[EE + e]], 1);
}

// ---------------------------------------------------------------------------
// CSR build step 2: exclusive scan of cnt[NN] -> off[NN] (+ off[NN]=EE),
// and cursor[i] = off[i].  Single block, 1024 threads (16 waves).
// ---------------------------------------------------------------------------
__global__ __launch_bounds__(1024) void scan_offsets(const int* __restrict__ cnt,
                                                     int* __restrict__ off,
                                                     int* __restrict__ cursor) {
    __shared__ int wsum[16];
    __shared__ int chunk_base;
    const int t = threadIdx.x;
    const int wave = t >> 6, lane = t & 63;
    if (t == 0) chunk_base = 0;
    __syncthreads();
    for (int base = 0; base < NN; base += 1024) {
        const int i = base + t;
        const int v = (i < NN) ? cnt[i] : 0;
        int s = v;
        #pragma unroll
        for (int o = 1; o < 64; o <<= 1) {
            int u = __shfl_up(s, o);
            if (lane >= o) s += u;
        }
        if (lane == 63) wsum[wave] = s;
        __syncthreads();
        if (wave == 0 && lane < 16) {
            int ss = wsum[lane];
            #pragma unroll
            for (int o = 1; o < 16; o <<= 1) {
                int u = __shfl_up(ss, o);
                if (lane >= o) ss += u;
            }
            wsum[lane] = ss;
        }
        __syncthreads();
        const int waveoff = (wave == 0) ? 0 : wsum[wave - 1];
        const int excl = chunk_base + waveoff + s - v;
        if (i < NN) { off[i] = excl; cursor[i] = excl; }
        __syncthreads();
        if (t == 0) chunk_base += wsum[15];
        __syncthreads();
    }
    if (t == 0) off[NN] = EE;
}

// ---------------------------------------------------------------------------
// CSR build step 3: scatter src ids into dst buckets.
// ---------------------------------------------------------------------------
__global__ __launch_bounds__(256) void scatter(const int* __restrict__ ei,
                                               int* __restrict__ cursor,
                                               int* __restrict__ psrc) {
    const unsigned e = blockIdx.x * 256u + threadIdx.x;
    if (e < EE) {
        const int dst = ei[EE + e];
        const int pos = atomicAdd(&cursor[dst], 1);
        psrc[pos] = ei[e];
    }
}

// ---------------------------------------------------------------------------
// Fused per-destination attention: one WAVE per dst node.
// Q,K,V all gathered as bf16 (512B/row).  2-edge unroll: all four gathers
// (K0,K1,V0,V1) issued before the dependent reduce/exp chain for MLP.
// psrc read in coalesced 64-chunks + shfl broadcast. Max-free softmax
// (clamp +-5 -> exact to ~1e-12).
// ---------------------------------------------------------------------------
__global__ __launch_bounds__(256) void agg_csr(const unsigned short* __restrict__ Qb,
                                               const unsigned short* __restrict__ Kb,
                                               const unsigned short* __restrict__ Vb,
                                               const int* __restrict__ off,
                                               const int* __restrict__ psrc,
                                               float* __restrict__ out) {
    const unsigned gid = blockIdx.x * 256u + threadIdx.x;   // exactly NN*64
    const int n = gid >> 6;
    const int r = gid & 63;
    const ushort4 qu = *(const ushort4*)(Qb + (size_t)n * DMODEL + r * 4);
    const float qs = 0.17677669529663687f;   // 1/sqrt(32) folded into Q
    const float qx = bf2f(qu.x) * qs, qy = bf2f(qu.y) * qs;
    const float qz = bf2f(qu.z) * qs, qw = bf2f(qu.w) * qs;
    float4 acc = make_float4(0.f, 0.f, 0.f, 0.f);
    float wsum = 0.f;
    const int j0 = off[n], j1 = off[n + 1];
    for (int base = j0; base < j1; base += 64) {
        const int m = j1 - base < 64 ? j1 - base : 64;
        const int sv = (base + r < j1) ? psrc[base + r] : 0;
        int i = 0;
        for (; i + 1 < m; i += 2) {
            const int src0 = __shfl(sv, i);
            const int src1 = __shfl(sv, i + 1);
            const ushort4 ku0 = *(const ushort4*)(Kb + (size_t)src0 * DMODEL + r * 4);
            const ushort4 ku1 = *(const ushort4*)(Kb + (size_t)src1 * DMODEL + r * 4);
            const ushort4 vu0 = *(const ushort4*)(Vb + (size_t)src0 * DMODEL + r * 4);
            const ushort4 vu1 = *(const ushort4*)(Vb + (size_t)src1 * DMODEL + r * 4);
            float p0 = bf2f(ku0.x) * qx;
            p0 = fmaf(bf2f(ku0.y), qy, p0);
            p0 = fmaf(bf2f(ku0.z), qz, p0);
            p0 = fmaf(bf2f(ku0.w), qw, p0);
            float p1 = bf2f(ku1.x) * qx;
            p1 = fmaf(bf2f(ku1.y), qy, p1);
            p1 = fmaf(bf2f(ku1.z), qz, p1);
            p1 = fmaf(bf2f(ku1.w), qw, p1);
            p0 += __shfl_xor(p0, 1);  p1 += __shfl_xor(p1, 1);
            p0 += __shfl_xor(p0, 2);  p1 += __shfl_xor(p1, 2);
            p0 += __shfl_xor(p0, 4);  p1 += __shfl_xor(p1, 4);
            const float w0 = expf(fminf(fmaxf(p0, -5.f), 5.f));
            const float w1 = expf(fminf(fmaxf(p1, -5.f), 5.f));
            acc.x = fmaf(w0, bf2f(vu0.x), acc.x);
            acc.y = fmaf(w0, bf2f(vu0.y), acc.y);
            acc.z = fmaf(w0, bf2f(vu0.z), acc.z);
            acc.w = fmaf(w0, bf2f(vu0.w), acc.w);
            wsum += w0;
            acc.x = fmaf(w1, bf2f(vu1.x), acc.x);
            acc.y = fmaf(w1, bf2f(vu1.y), acc.y);
            acc.z = fmaf(w1, bf2f(vu1.z), acc.z);
            acc.w = fmaf(w1, bf2f(vu1.w), acc.w);
            wsum += w1;
        }
        if (i < m) {
            const int src = __shfl(sv, i);
            const ushort4 ku = *(const ushort4*)(Kb + (size_t)src * DMODEL + r * 4);
            const ushort4 vu = *(const ushort4*)(Vb + (size_t)src * DMODEL + r * 4);
            float p = bf2f(ku.x) * qx;
            p = fmaf(bf2f(ku.y), qy, p);
            p = fmaf(bf2f(ku.z), qz, p);
            p = fmaf(bf2f(ku.w), qw, p);
            p += __shfl_xor(p, 1);
            p += __shfl_xor(p, 2);
            p += __shfl_xor(p, 4);
            const float wv = expf(fminf(fmaxf(p, -5.f), 5.f));
            acc.x = fmaf(wv, bf2f(vu.x), acc.x);
            acc.y = fmaf(wv, bf2f(vu.y), acc.y);
            acc.z = fmaf(wv, bf2f(vu.z), acc.z);
            acc.w = fmaf(wv, bf2f(vu.w), acc.w);
            wsum += wv;
        }
    }
    const float inv = 1.0f / (wsum + 1e-16f);
    float4 o;
    o.x = acc.x * inv; o.y = acc.y * inv; o.z = acc.z * inv; o.w = acc.w * inv;
    *(float4*)(out + (size_t)n * DMODEL + r * 4) = o;
}

// ---------------------------------------------------------------------------
extern "C" void kernel_launch(void* const* d_in, const int* in_sizes, int n_in,
                              void* d_out, int out_size, void* d_ws, size_t ws_size,
                              hipStream_t stream) {
    (void)in_sizes; (void)n_in; (void)out_size; (void)ws_size;
    const float* x    = (const float*)d_in[0];
    const float* ang  = (const float*)d_in[1];
    const int*   ei   = (const int*)d_in[2];
    const float* Wq   = (const float*)d_in[3];
    const float* bq   = (const float*)d_in[4];
    const float* Wk   = (const float*)d_in[5];
    const float* bk   = (const float*)d_in[6];
    const float* Wv   = (const float*)d_in[7];
    const float* bv   = (const float*)d_in[8];
    const float* S    = (const float*)d_in[9];
    float* out = (float*)d_out;
    float* ws  = (float*)d_ws;

    float* P = ws + P_OFF;
    unsigned short* Qb = (unsigned short*)(ws + QB_OFF);
    unsigned short* Kb = (unsigned short*)(ws + KB_OFF);
    unsigned short* Vb = (unsigned short*)(ws + V_OFF);
    int* iws    = (int*)(ws + INT_OFF);
    int* cnt    = iws + CNT_I;
    int* off    = iws + OFF_I;
    int* cursor = iws + CUR_I;
    int* psrc   = iws + PSRC_I;
    short* wt_hi = (short*)(ws + WTH_OFF);
    short* wt_lo = (short*)(ws + WTL_OFF);

    // zero the histogram (d_ws is poisoned before every call)
    hipMemsetAsync(cnt, 0, (size_t)NN * sizeof(int), stream);

    softmax_S<<<1, 512, 0, stream>>>(S, P);

    split_wt<<<768, 256, 0, stream>>>(Wq, Wk, Wv, wt_hi, wt_lo);

    dim3 ggrid((NN + 63) / 64, 4);
    qkv_mfma<<<ggrid, 256, 0, stream>>>(x, wt_hi, wt_lo, bq, bk, bv, Qb, Kb, Vb);

    rotate_qk<<<(NN + 31) / 32, 256, 0, stream>>>(Qb, Kb, ang, P);

    hist<<<(EE + 255) / 256, 256, 0, stream>>>(ei, cnt);
    scan_offsets<<<1, 1024, 0, stream>>>(cnt, off, cursor);
    scatter<<<(EE + 255) / 256, 256, 0, stream>>>(ei, cursor, psrc);

    agg_csr<<<(NN * 64) / 256, 256, 0, stream>>>(Qb, Kb, Vb, off, psrc, out);
}